// Round 10
// baseline (215.382 us; speedup 1.0000x reference)
//
#include <hip/hip_runtime.h>

namespace {

constexpr int BD = 2;
constexpr int DD = 160, HH = 192, WW = 224;
constexpr float INV_WIN = 1.0f / 729.0f;
constexpr float EPSV = 1e-5f;

constexpr int TH = 16, TW = 16;          // output tile (H x W)
constexpr int DC = 16;                   // output planes per d-chunk
constexpr int NREAL = DC + 8;            // 24 plane steps = 12 pairs
constexpr int NPAIR = NREAL / 2;         // 12; superstep loop runs 13 (pipelined)
constexpr int NCH = DD / DC;             // 10
constexpr int GX = WW / TW;              // 14
constexpr int GY = HH / TH;              // 12
constexpr int GZ = BD * NCH;             // 20
constexpr int NBLK = GX * GY * GZ;       // 3360
constexpr int NXCD = 8;
constexpr int CPX = NBLK / NXCD;         // 420 (3360 % 8 == 0 -> bijective swizzle)
constexpr double NTOT = (double)BD * DD * HH * WW;

// srow (R10 RELAYOUT, w-innermost): [buf][plane][field][row][w0..15 pad 20].
// Purpose: S2's 4 sliding sums per field are w-CONTIGUOUS -> 5x ds_write_b128
// per thread (was 20x ds_write_b32). This shortens the phase-A pacer stream
// (waves 1-2 issue S2+S3 both) and cuts the busiest pipe (LDS ~66% busy).
// S3 column reads become 24 strided b32 (row stride 80 B; combiner pairs
// rows 0-12 / 13-23 into ~12 ds_read2_b32).
// Bank audit: S2 b128 quad = (4*p2 + 4*f + 5*r2 + seg) mod 8 -> exactly
//   8 lanes/quad = b128 floor (conflict-free). S3 read bank =
//   (16*p3 + 16*f3 + wl3 + 20*r) mod 32 -> exactly 2 lanes/bank (free b32
//   floor) for all S3 waves incl. straddles — requires SR_FS == 16 mod 32
//   and SR_PL == 16 mod 32 (496, 2480 chosen for this).
constexpr int SR_RS = 20;                // row stride (16 w + pad 4)
constexpr int SR_FS = 496;               // field stride (24*20=480 + pad 16)
constexpr int SR_PL = 2480;              // plane stride (5*496; ==16 mod 32)
// scol (R9 layout, measured neutral — kept): [w][plane][field][oh], pad 4.
// S3 b128 writes uniform /quad; S4 b32 reads exactly 2/bank; S4's 10 loads
// share one base (imms 0..180 dw, read2-reachable).
constexpr int SC_F = 20;
constexpr int SC_P = 100;
constexpr int SC_W = 204;
constexpr int SC_SZ = 16 * SC_W;         // 3264 floats = 13056 B

} // namespace

// R8 structure (best: fused 101.3-101.5 us, total 193.5) + srow transpose.
// Session model (10 measurements): dur x VALUBusy ~= 46 us (fixed VALU work);
// superstep wall ~4280 cyc paced by phase A's longest wave-stream (waves 1-2
// issue S2 AND S3); per-CU pipes: LDS ~66% busy, VALU 45%, HBM 9% — nothing
// saturated, latency/issue-bound. R9 (scol read2 relayout) was NULL because
// S4 sits in the slack phase B — cuts must target PHASE A (this round: S2
// writes 20->5 instrs on the pacer waves).
// DO NOT (measured): min-waves launch_bounds (R1 spill 3x); single-plane
// epochs (R2 1.65x); one-shot grid / rolled loop (R3 1.6x); 512-thr blocks
// (R4); DC>16 (R5 VGPR 128); phase-repacked 5-blk residency (R6 flat);
// 1-barrier merge (R7 flat); S4-phase LDS cuts (R9 null — slack phase).
__global__ __launch_bounds__(256)
void ncc_fused(const float* __restrict__ x, const float* __restrict__ y,
               float* __restrict__ bsum) {
  const int tid = threadIdx.x;

  // XCD-chunked swizzle: halo re-reads hit same-XCD L2 (~200cy) not HBM
  // (~900cy). Proven: FETCH 348->75 MB, fused 115->101.5 on this structure.
  const int lid = (int)blockIdx.x;
  const int nl  = (lid & (NXCD - 1)) * CPX + (lid >> 3);
  const int zb  = nl / (GX * GY);
  const int rem = nl - zb * (GX * GY);
  const int by  = rem / GX;
  const int bx  = rem - by * GX;

  const int w0 = bx * TW;
  const int h0 = by * TH;
  const int b  = zb / NCH;
  const int d0 = (zb - b * NCH) * DC;

  __shared__ __align__(16) float srowF[2][2 * SR_PL];  // 39680 B (pair dbuf)
  __shared__ __align__(16) float scolF[SC_SZ];         // 13056 B
  __shared__ float swsum[4];
  // total ~52.8 KB -> still 3 blocks/CU (160/52.8 = 3.03)

  // ---- S2 roles: tids 0..191 = 2 planes x 24 rows x 4 col-segments,
  // 12-wide register window -> 4 sliding 9-tap W-sums x 5 fields.
  const bool s2a = tid < 192;
  const int p2  = tid / 96;
  const int t96 = tid - 96 * p2;
  const int r2  = t96 >> 2;            // input row 0..23
  const int seg = tid & 3;
  const int gh  = h0 - 4 + r2;
  const int gw0 = w0 - 4 + seg * 4;    // 16B aligned
  const bool hok = (unsigned)gh < (unsigned)HH;
  const bool fastw = (gw0 >= 0) && (gw0 + 11 < WW);
  const unsigned plane = (unsigned)HH * WW;

  auto prefetch = [&](int s, float4* vx, float4* vy) {
    const int din = d0 - 4 + s;
    const float4 z = make_float4(0.f, 0.f, 0.f, 0.f);
    vx[0] = vx[1] = vx[2] = z;
    vy[0] = vy[1] = vy[2] = z;
    if (s2a && hok && (s < NREAL) && (din >= 0) && (din < DD)) {
      const unsigned rb = ((unsigned)b * DD + (unsigned)din) * plane + (unsigned)gh * WW;
      if (fastw) {
        const float4* px = (const float4*)(x + rb + gw0);
        const float4* py = (const float4*)(y + rb + gw0);
        vx[0] = px[0]; vx[1] = px[1]; vx[2] = px[2];
        vy[0] = py[0]; vy[1] = py[1]; vy[2] = py[2];
      } else {
        float* fx = (float*)vx;
        float* fy = (float*)vy;
#pragma unroll
        for (int e = 0; e < 12; ++e) {
          const int gw = gw0 + e;
          if ((unsigned)gw < (unsigned)WW) {
            fx[e] = x[rb + gw];
            fy[e] = y[rb + gw];
          }
        }
      }
    }
  };

  // ---- S3 roles: tids 96..255 = 2 planes x 5 fields x 16 w (wave balance:
  // wave0 S2-only, wave3 S3-only, waves1-2 mixed = the barrier pacers).
  const int t3  = tid - 96;
  const int p3  = t3 / 80;
  const int r3  = t3 - 80 * p3;
  const int f3  = r3 >> 4;
  const int wl3 = r3 & 15;

  const int ow = tid & 15;
  const int oh = tid >> 4;

  // D-ring: 9 slots x 5 fields; slot indices static after full unroll.
  float rg0[9], rg1[9], rg2[9], rg3[9], rg4[9];
#pragma unroll
  for (int k = 0; k < 9; ++k) { rg0[k]=0.f; rg1[k]=0.f; rg2[k]=0.f; rg3[k]=0.f; rg4[k]=0.f; }
  float a0=0.f, a1=0.f, a2=0.f, a3=0.f, a4=0.f;
  float lsum = 0.0f;

  float4 px4[3], py4[3];
  prefetch(p2, px4, py4);               // pair 0

  // Pipelined supersteps: S2 stages pair ss; S3/S4 consume pair ss-1.
#pragma unroll
  for (int ss = 0; ss <= NPAIR; ++ss) {
    // prefetch pair ss+1 (consumed by S2 next superstep)
    float4 nx4[3], ny4[3];
    if (ss + 1 < NPAIR) prefetch(2 * (ss + 1) + p2, nx4, ny4);

    // ---- S2 (pair ss): W-sums -> srow[ss&1]. Independent of S3 below.
    if (ss < NPAIR && s2a) {
      float xv[12], yv[12];
#pragma unroll
      for (int k = 0; k < 3; ++k) {
        *(float4*)&xv[4 * k] = px4[k];
        *(float4*)&yv[4 * k] = py4[k];
      }
      // collect the 4 sliding positions per field, then write 5x b128
      float wv0[4], wv1[4], wv2[4], wv3[4], wv4[4];
      float s0=0.f, s1=0.f, s2=0.f, s3=0.f, s4=0.f;
#pragma unroll
      for (int k = 0; k < 9; ++k) {
        s0 += xv[k]; s1 += yv[k];
        s2 = fmaf(xv[k], xv[k], s2);
        s3 = fmaf(yv[k], yv[k], s3);
        s4 = fmaf(xv[k], yv[k], s4);
      }
      wv0[0] = s0; wv1[0] = s1; wv2[0] = s2; wv3[0] = s3; wv4[0] = s4;
#pragma unroll
      for (int t = 1; t < 4; ++t) {
        const float xn = xv[8 + t], xo = xv[t - 1];
        const float yn = yv[8 + t], yo = yv[t - 1];
        s0 += xn - xo;
        s1 += yn - yo;
        s2 += fmaf(xn, xn, -(xo * xo));
        s3 += fmaf(yn, yn, -(yo * yo));
        s4 += fmaf(xn, yn, -(xo * yo));
        wv0[t] = s0; wv1[t] = s1; wv2[t] = s2; wv3[t] = s3; wv4[t] = s4;
      }
      // w-contiguous: dw = p2*SR_PL + f*SR_FS + r2*SR_RS + seg*4 (16B aligned)
      float* wb = &srowF[ss & 1][p2 * SR_PL + r2 * SR_RS + seg * 4];
      *(float4*)&wb[0 * SR_FS] = make_float4(wv0[0], wv0[1], wv0[2], wv0[3]);
      *(float4*)&wb[1 * SR_FS] = make_float4(wv1[0], wv1[1], wv1[2], wv1[3]);
      *(float4*)&wb[2 * SR_FS] = make_float4(wv2[0], wv2[1], wv2[2], wv2[3]);
      *(float4*)&wb[3 * SR_FS] = make_float4(wv3[0], wv3[1], wv3[2], wv3[3]);
      *(float4*)&wb[4 * SR_FS] = make_float4(wv4[0], wv4[1], wv4[2], wv4[3]);
    }

    // ---- S3 (pair ss-1): H-sums from srow[(ss-1)&1] -> scol.
    // Column read at fixed w: 24 b32 at row stride 20 dw (80 B) — the
    // DS-combiner pairs these into ds_read2_b32 (stride < 255-dw reach).
    if (ss >= 1 && tid >= 96) {
      const float* rp = &srowF[(ss - 1) & 1][p3 * SR_PL + f3 * SR_FS + wl3];
      float rv[24];
#pragma unroll
      for (int r = 0; r < 24; ++r) rv[r] = rp[r * SR_RS];
      float acc = rv[0];
#pragma unroll
      for (int t = 1; t < 9; ++t) acc += rv[t];
      float ov[16];
      ov[0] = acc;
#pragma unroll
      for (int o = 1; o < 16; ++o) { acc += rv[o + 8] - rv[o - 1]; ov[o] = acc; }
      float* cp = &scolF[wl3 * SC_W + p3 * SC_P + f3 * SC_F];
#pragma unroll
      for (int t = 0; t < 4; ++t)
        *(float4*)&cp[4 * t] = make_float4(ov[4*t], ov[4*t+1], ov[4*t+2], ov[4*t+3]);
    }
    __syncthreads();   // C: scol visible (also orders S2 writes vs next S3)

    // ---- S4 (pair ss-1): ring update + emit (all 256 threads).
    if (ss >= 1) {
      const int sA  = 2 * (ss - 1);
      const int sB  = sA + 1;
      const int slA = sA % 9;
      const int slB = sB % 9;
      const float* c = &scolF[ow * SC_W + oh];
      const float gA0 = c[0*SC_F],          gA1 = c[1*SC_F],          gA2 = c[2*SC_F],
                  gA3 = c[3*SC_F],          gA4 = c[4*SC_F];
      const float gB0 = c[SC_P + 0*SC_F],   gB1 = c[SC_P + 1*SC_F],   gB2 = c[SC_P + 2*SC_F],
                  gB3 = c[SC_P + 3*SC_F],   gB4 = c[SC_P + 4*SC_F];

      a0 += gA0 - rg0[slA]; rg0[slA] = gA0;
      a1 += gA1 - rg1[slA]; rg1[slA] = gA1;
      a2 += gA2 - rg2[slA]; rg2[slA] = gA2;
      a3 += gA3 - rg3[slA]; rg3[slA] = gA3;
      a4 += gA4 - rg4[slA]; rg4[slA] = gA4;
      if (sA >= 8) {
        const float cross = fmaf(-a0 * INV_WIN, a1, a4);
        const float iv = fmaxf(fmaf(-a0 * INV_WIN, a0, a2), EPSV);
        const float jv = fmaxf(fmaf(-a1 * INV_WIN, a1, a3), EPSV);
        lsum += (cross * cross) / (iv * jv);
      }
      a0 += gB0 - rg0[slB]; rg0[slB] = gB0;
      a1 += gB1 - rg1[slB]; rg1[slB] = gB1;
      a2 += gB2 - rg2[slB]; rg2[slB] = gB2;
      a3 += gB3 - rg3[slB]; rg3[slB] = gB3;
      a4 += gB4 - rg4[slB]; rg4[slB] = gB4;
      if (sB >= 8) {
        const float cross = fmaf(-a0 * INV_WIN, a1, a4);
        const float iv = fmaxf(fmaf(-a0 * INV_WIN, a0, a2), EPSV);
        const float jv = fmaxf(fmaf(-a1 * INV_WIN, a1, a3), EPSV);
        lsum += (cross * cross) / (iv * jv);
      }
    }
    __syncthreads();   // E: S4 scol-reads done before S3(ss+1) overwrites;
                       //    S2(ss) srow writes visible to S3(ss+1).
    if (ss + 1 < NPAIR) {
#pragma unroll
      for (int k = 0; k < 3; ++k) { px4[k] = nx4[k]; py4[k] = ny4[k]; }
    }
  }

  // ---- block reduction
#pragma unroll
  for (int off = 32; off > 0; off >>= 1) lsum += __shfl_down(lsum, off);
  if ((tid & 63) == 0) swsum[tid >> 6] = lsum;
  __syncthreads();
  if (tid == 0) bsum[nl] = swsum[0] + swsum[1] + swsum[2] + swsum[3];
}

__global__ __launch_bounds__(256)
void ncc_finalize(const float* __restrict__ bsum, float* __restrict__ out) {
  double s = 0.0;
  for (int i = threadIdx.x; i < NBLK; i += 256) s += (double)bsum[i];
#pragma unroll
  for (int off = 32; off > 0; off >>= 1) s += __shfl_down(s, off);
  __shared__ double sh[4];
  if ((threadIdx.x & 63) == 0) sh[threadIdx.x >> 6] = s;
  __syncthreads();
  if (threadIdx.x == 0)
    out[0] = (float)(-(sh[0] + sh[1] + sh[2] + sh[3]) / NTOT);
}

extern "C" void kernel_launch(void* const* d_in, const int* in_sizes, int n_in,
                              void* d_out, int out_size, void* d_ws, size_t ws_size,
                              hipStream_t stream) {
  const float* x = (const float*)d_in[0];
  const float* y = (const float*)d_in[1];
  float* bsum = (float*)d_ws;          // 3360 floats, fully rewritten every call
  float* out  = (float*)d_out;

  dim3 grid(NBLK);
  ncc_fused<<<grid, dim3(256), 0, stream>>>(x, y, bsum);
  ncc_finalize<<<1, dim3(256), 0, stream>>>(bsum, out);
}

// Round 11
// 193.591 us; speedup vs baseline: 1.1126x; 1.1126x over previous
//
#include <hip/hip_runtime.h>

namespace {

constexpr int BD = 2;
constexpr int DD = 160, HH = 192, WW = 224;
constexpr float INV_WIN = 1.0f / 729.0f;
constexpr float EPSV = 1e-5f;

constexpr int TH = 16, TW = 16;          // output tile (H x W)
constexpr int DC = 16;                   // output planes per d-chunk
constexpr int NREAL = DC + 8;            // 24 plane steps = 12 pairs
constexpr int NPAIR = NREAL / 2;         // 12; superstep loop runs 13 (pipelined)
constexpr int NCH = DD / DC;             // 10
constexpr int GX = WW / TW;              // 14
constexpr int GY = HH / TH;              // 12
constexpr int GZ = BD * NCH;             // 20
constexpr int NBLK = GX * GY * GZ;       // 3360
constexpr int NXCD = 8;
constexpr int CPX = NBLK / NXCD;         // 420 (3360 % 8 == 0 -> bijective swizzle)
constexpr double NTOT = (double)BD * DD * HH * WW;

// srow: [buf][plane][field][w*28 + row], rows 0..23 contiguous (pad 28).
// SR_FS=452 (f-shift /4=113==1 mod 8), SR_PL=2280 (==8 mod 32). Audited:
// S2 b32 scatter 2/bank (free floor, m136); S3 b128 reads uniform /quad.
// R10 lesson: do NOT transpose this to w-innermost — S2's write count drops
// but S3's read stream widens 6xb128 -> ~12xread2 and S2 loses its
// compute/write interleave ILP; net 101 -> 125 us.
constexpr int SR_FS = 452;
constexpr int SR_PL = 2280;
// scol: [plane][field][w*20 + o]. SC_FS=324, SC_PL=1620. S3 b128 writes
// uniform /quad; S4 b32 reads exactly 2/bank. R9 lesson: S4-side read2
// relayout is NULL — S4 sits in the slack phase B.
constexpr int SC_FS = 324;
constexpr int SC_PL = 1620;

} // namespace

// R8 kernel VERBATIM (session best: fused 101.3 us, total 193.5) + ONE
// delta: s_setprio(1) on the pacer waves. Per-superstep issue streams
// (exec-masking does not skip issue): wave0 S2+S4 ~155 instr, waves1-2
// S2+S3+S4 ~211 (the streams every barrier waits on), wave3 S3+S4 ~106.
// With 3 independent blocks/CU (12 waves, 4 roles) the CU scheduler has
// role diversity -> prioritizing the pacer streams shortens every barrier
// interval (T5 evidence: pays with role-diverse waves, ~free otherwise).
// Session model (11 measurements): dur x VALUBusy ~= 46 us fixed VALU work;
// latency/issue-bound (HBM 9%, LDS ~66%, VALU 45% — nothing saturated).
// DO NOT (all measured): min-waves launch_bounds (R1 spill 3x); single-plane
// epochs (R2 1.65x); one-shot grid/rolled loop (R3 1.6x); 512-thr blocks
// (R4); DC>16 (R5); 5-blk repack (R6 flat); 1-barrier merge (R7 flat);
// S4 read2 relayout (R9 null); srow transpose (R10 -24%).
__global__ __launch_bounds__(256)
void ncc_fused(const float* __restrict__ x, const float* __restrict__ y,
               float* __restrict__ bsum) {
  const int tid = threadIdx.x;

  // R11: pacer-wave priority (wave-uniform branch; persists for the kernel).
  const int wv = tid >> 6;
  if (wv == 1 || wv == 2) __builtin_amdgcn_s_setprio(1);

  // XCD-chunked swizzle: halo re-reads hit same-XCD L2 (~200cy) not HBM
  // (~900cy). Proven: FETCH 348->75 MB, fused 115->101.5 on this structure.
  const int lid = (int)blockIdx.x;
  const int nl  = (lid & (NXCD - 1)) * CPX + (lid >> 3);
  const int zb  = nl / (GX * GY);
  const int rem = nl - zb * (GX * GY);
  const int by  = rem / GX;
  const int bx  = rem - by * GX;

  const int w0 = bx * TW;
  const int h0 = by * TH;
  const int b  = zb / NCH;
  const int d0 = (zb - b * NCH) * DC;

  __shared__ __align__(16) float srowF[2][2 * SR_PL];  // 36480 B (pair dbuf)
  __shared__ __align__(16) float scolF[2 * SC_PL];     // 12960 B
  __shared__ float swsum[4];

  // ---- S2 roles: tids 0..191 = 2 planes x 24 rows x 4 col-segments,
  // 12-wide register window -> 4 sliding 9-tap W-sums x 5 fields.
  const bool s2a = tid < 192;
  const int p2  = tid / 96;
  const int t96 = tid - 96 * p2;
  const int r2  = t96 >> 2;            // input row 0..23
  const int seg = tid & 3;
  const int gh  = h0 - 4 + r2;
  const int gw0 = w0 - 4 + seg * 4;    // 16B aligned
  const bool hok = (unsigned)gh < (unsigned)HH;
  const bool fastw = (gw0 >= 0) && (gw0 + 11 < WW);
  const unsigned plane = (unsigned)HH * WW;

  auto prefetch = [&](int s, float4* vx, float4* vy) {
    const int din = d0 - 4 + s;
    const float4 z = make_float4(0.f, 0.f, 0.f, 0.f);
    vx[0] = vx[1] = vx[2] = z;
    vy[0] = vy[1] = vy[2] = z;
    if (s2a && hok && (s < NREAL) && (din >= 0) && (din < DD)) {
      const unsigned rb = ((unsigned)b * DD + (unsigned)din) * plane + (unsigned)gh * WW;
      if (fastw) {
        const float4* px = (const float4*)(x + rb + gw0);
        const float4* py = (const float4*)(y + rb + gw0);
        vx[0] = px[0]; vx[1] = px[1]; vx[2] = px[2];
        vy[0] = py[0]; vy[1] = py[1]; vy[2] = py[2];
      } else {
        float* fx = (float*)vx;
        float* fy = (float*)vy;
#pragma unroll
        for (int e = 0; e < 12; ++e) {
          const int gw = gw0 + e;
          if ((unsigned)gw < (unsigned)WW) {
            fx[e] = x[rb + gw];
            fy[e] = y[rb + gw];
          }
        }
      }
    }
  };

  // ---- S3 roles: tids 96..255 = 2 planes x 5 fields x 16 w (wave balance:
  // wave0 S2-only, wave3 S3-only, waves1-2 mixed = the barrier pacers).
  const int t3  = tid - 96;
  const int p3  = t3 / 80;
  const int r3  = t3 - 80 * p3;
  const int f3  = r3 >> 4;
  const int wl3 = r3 & 15;

  const int ow = tid & 15;
  const int oh = tid >> 4;

  // D-ring: 9 slots x 5 fields; slot indices static after full unroll.
  float rg0[9], rg1[9], rg2[9], rg3[9], rg4[9];
#pragma unroll
  for (int k = 0; k < 9; ++k) { rg0[k]=0.f; rg1[k]=0.f; rg2[k]=0.f; rg3[k]=0.f; rg4[k]=0.f; }
  float a0=0.f, a1=0.f, a2=0.f, a3=0.f, a4=0.f;
  float lsum = 0.0f;

  float4 px4[3], py4[3];
  prefetch(p2, px4, py4);               // pair 0

  // Pipelined supersteps: S2 stages pair ss; S3/S4 consume pair ss-1.
#pragma unroll
  for (int ss = 0; ss <= NPAIR; ++ss) {
    // prefetch pair ss+1 (consumed by S2 next superstep)
    float4 nx4[3], ny4[3];
    if (ss + 1 < NPAIR) prefetch(2 * (ss + 1) + p2, nx4, ny4);

    // ---- S2 (pair ss): W-sums -> srow[ss&1]. Independent of S3 below.
    if (ss < NPAIR && s2a) {
      float xv[12], yv[12];
#pragma unroll
      for (int k = 0; k < 3; ++k) {
        *(float4*)&xv[4 * k] = px4[k];
        *(float4*)&yv[4 * k] = py4[k];
      }
      float s0=0.f, s1=0.f, s2=0.f, s3=0.f, s4=0.f;
#pragma unroll
      for (int k = 0; k < 9; ++k) {
        s0 += xv[k]; s1 += yv[k];
        s2 = fmaf(xv[k], xv[k], s2);
        s3 = fmaf(yv[k], yv[k], s3);
        s4 = fmaf(xv[k], yv[k], s4);
      }
      float* wb = &srowF[ss & 1][p2 * SR_PL + (seg * 4) * 28 + r2];
      wb[0 * SR_FS] = s0; wb[1 * SR_FS] = s1; wb[2 * SR_FS] = s2;
      wb[3 * SR_FS] = s3; wb[4 * SR_FS] = s4;
#pragma unroll
      for (int t = 1; t < 4; ++t) {
        const float xn = xv[8 + t], xo = xv[t - 1];
        const float yn = yv[8 + t], yo = yv[t - 1];
        s0 += xn - xo;
        s1 += yn - yo;
        s2 += fmaf(xn, xn, -(xo * xo));
        s3 += fmaf(yn, yn, -(yo * yo));
        s4 += fmaf(xn, yn, -(xo * yo));
        float* wt = wb + t * 28;
        wt[0 * SR_FS] = s0; wt[1 * SR_FS] = s1; wt[2 * SR_FS] = s2;
        wt[3 * SR_FS] = s3; wt[4 * SR_FS] = s4;
      }
    }

    // ---- S3 (pair ss-1): H-sums from srow[(ss-1)&1] -> scol.
    // No barrier needed vs S2: different srow buffer (written last superstep,
    // separated by barrier E(ss-1)).
    if (ss >= 1 && tid >= 96) {
      const float* rp = &srowF[(ss - 1) & 1][p3 * SR_PL + f3 * SR_FS + wl3 * 28];
      float rv[24];
#pragma unroll
      for (int t = 0; t < 6; ++t) *(float4*)&rv[4 * t] = *(const float4*)&rp[4 * t];
      float acc = rv[0];
#pragma unroll
      for (int t = 1; t < 9; ++t) acc += rv[t];
      float ov[16];
      ov[0] = acc;
#pragma unroll
      for (int o = 1; o < 16; ++o) { acc += rv[o + 8] - rv[o - 1]; ov[o] = acc; }
      float* cp = &scolF[p3 * SC_PL + f3 * SC_FS + wl3 * 20];
#pragma unroll
      for (int t = 0; t < 4; ++t)
        *(float4*)&cp[4 * t] = make_float4(ov[4*t], ov[4*t+1], ov[4*t+2], ov[4*t+3]);
    }
    __syncthreads();   // C: scol visible (also orders S2 writes vs next S3)

    // ---- S4 (pair ss-1): ring update + emit (all 256 threads)
    if (ss >= 1) {
      const int sA  = 2 * (ss - 1);
      const int sB  = sA + 1;
      const int slA = sA % 9;
      const int slB = sB % 9;
      const float* cA = &scolF[ow * 20 + oh];
      const float* cB = cA + SC_PL;
      const float gA0 = cA[0*SC_FS], gA1 = cA[1*SC_FS], gA2 = cA[2*SC_FS],
                  gA3 = cA[3*SC_FS], gA4 = cA[4*SC_FS];
      const float gB0 = cB[0*SC_FS], gB1 = cB[1*SC_FS], gB2 = cB[2*SC_FS],
                  gB3 = cB[3*SC_FS], gB4 = cB[4*SC_FS];

      a0 += gA0 - rg0[slA]; rg0[slA] = gA0;
      a1 += gA1 - rg1[slA]; rg1[slA] = gA1;
      a2 += gA2 - rg2[slA]; rg2[slA] = gA2;
      a3 += gA3 - rg3[slA]; rg3[slA] = gA3;
      a4 += gA4 - rg4[slA]; rg4[slA] = gA4;
      if (sA >= 8) {
        const float cross = fmaf(-a0 * INV_WIN, a1, a4);
        const float iv = fmaxf(fmaf(-a0 * INV_WIN, a0, a2), EPSV);
        const float jv = fmaxf(fmaf(-a1 * INV_WIN, a1, a3), EPSV);
        lsum += (cross * cross) / (iv * jv);
      }
      a0 += gB0 - rg0[slB]; rg0[slB] = gB0;
      a1 += gB1 - rg1[slB]; rg1[slB] = gB1;
      a2 += gB2 - rg2[slB]; rg2[slB] = gB2;
      a3 += gB3 - rg3[slB]; rg3[slB] = gB3;
      a4 += gB4 - rg4[slB]; rg4[slB] = gB4;
      if (sB >= 8) {
        const float cross = fmaf(-a0 * INV_WIN, a1, a4);
        const float iv = fmaxf(fmaf(-a0 * INV_WIN, a0, a2), EPSV);
        const float jv = fmaxf(fmaf(-a1 * INV_WIN, a1, a3), EPSV);
        lsum += (cross * cross) / (iv * jv);
      }
    }
    __syncthreads();   // E: S4 scol-reads done before S3(ss+1) overwrites;
                       //    S2(ss) srow writes visible to S3(ss+1).
    if (ss + 1 < NPAIR) {
#pragma unroll
      for (int k = 0; k < 3; ++k) { px4[k] = nx4[k]; py4[k] = ny4[k]; }
    }
  }

  // ---- block reduction
#pragma unroll
  for (int off = 32; off > 0; off >>= 1) lsum += __shfl_down(lsum, off);
  if ((tid & 63) == 0) swsum[tid >> 6] = lsum;
  __syncthreads();
  if (tid == 0) bsum[nl] = swsum[0] + swsum[1] + swsum[2] + swsum[3];
}

__global__ __launch_bounds__(256)
void ncc_finalize(const float* __restrict__ bsum, float* __restrict__ out) {
  double s = 0.0;
  for (int i = threadIdx.x; i < NBLK; i += 256) s += (double)bsum[i];
#pragma unroll
  for (int off = 32; off > 0; off >>= 1) s += __shfl_down(s, off);
  __shared__ double sh[4];
  if ((threadIdx.x & 63) == 0) sh[threadIdx.x >> 6] = s;
  __syncthreads();
  if (threadIdx.x == 0)
    out[0] = (float)(-(sh[0] + sh[1] + sh[2] + sh[3]) / NTOT);
}

extern "C" void kernel_launch(void* const* d_in, const int* in_sizes, int n_in,
                              void* d_out, int out_size, void* d_ws, size_t ws_size,
                              hipStream_t stream) {
  const float* x = (const float*)d_in[0];
  const float* y = (const float*)d_in[1];
  float* bsum = (float*)d_ws;          // 3360 floats, fully rewritten every call
  float* out  = (float*)d_out;

  dim3 grid(NBLK);
  ncc_fused<<<grid, dim3(256), 0, stream>>>(x, y, bsum);
  ncc_finalize<<<1, dim3(256), 0, stream>>>(bsum, out);
}